// Round 3
// baseline (366.066 us; speedup 1.0000x reference)
//
#include <hip/hip_runtime.h>

// Problem constants
#define BATCH   8
#define NNODES  16384
#define KNBR    16
#define LATENT  128
#define DOUT    32
#define NROWS   (BATCH * NNODES)          // 131072 rows total

// ---------------------------------------------------------------------------
// Kernel 1: fused ks/qs projection.  out[row][d] = dot(features[row], w[d]) + b[d]
// Block: 256 threads, 256 rows. Each thread: 8 rows x (4 k-outs + 4 q-outs).
// Features staged through LDS in 4 K-chunks of 32 floats with coalesced loads.
// LDS = 32KB features + 2x16KB weights = 64KB exactly -> 2 blocks/CU.
// XOR swizzles spread the 8-unique-addr x 8-way-broadcast compute reads over
// all 32 banks (without them, all 8 addrs land on one 4-bank group).
// ---------------------------------------------------------------------------
__global__ __launch_bounds__(256) void proj_kernel(
    const float* __restrict__ feats,
    const float* __restrict__ kw, const float* __restrict__ kb,
    const float* __restrict__ qw, const float* __restrict__ qb,
    float* __restrict__ out_k, float* __restrict__ out_q)
{
    __shared__ float4 fs4[256 * 8];       // 256 rows x 8 f4, col swizzled by (row>>3)&7
    __shared__ float4 wk_s[DOUT * 32];    // 32 d x 32 f4-cols, col swizzled by (d>>2)&7
    __shared__ float4 wq_s[DOUT * 32];

    const int tid = threadIdx.x;

    // Stage weights once (coalesced global read, swizzled LDS write)
    {
        float* wkf = (float*)wk_s;
        float* wqf = (float*)wq_s;
        for (int i = tid; i < DOUT * LATENT; i += 256) {
            const int d = i >> 7;           // 0..31
            const int l = i & 127;
            const int c = l >> 2;           // f4 column 0..31
            const int sub = l & 3;
            const int cs = c ^ ((d >> 2) & 7);
            wkf[d * 128 + cs * 4 + sub] = kw[i];
            wqf[d * 128 + cs * 4 + sub] = qw[i];
        }
    }

    const int d0 = tid & 7;      // output quad: k-outs 4*d0+j, q-outs 4*d0+j
    const int ro = tid >> 3;     // row group: rows ro*8 .. ro*8+7
    const long long blk_row = (long long)blockIdx.x * 256;

    const int s_rowg = tid >> 3; // 0..31 (staging row base)
    const int s_c8   = tid & 7;  // 0..7  (staging f4 column)

    float acc_k[8][4];
    float acc_q[8][4];
#pragma unroll
    for (int i = 0; i < 8; ++i)
#pragma unroll
        for (int j = 0; j < 4; ++j) { acc_k[i][j] = 0.f; acc_q[i][j] = 0.f; }

    const float4* f4 = (const float4*)feats;   // feature row stride = 32 float4

    for (int ch = 0; ch < 4; ++ch) {
        __syncthreads();   // protect fs4 (and, at ch=0, the weight stores)
        // Stage 256 rows x 8 float4 of chunk ch. Row stride in global = 32 f4.
#pragma unroll
        for (int i = 0; i < 8; ++i) {
            const int row = s_rowg + 32 * i;
            const int cs  = s_c8 ^ ((row >> 3) & 7);
            fs4[row * 8 + cs] = f4[(blk_row + row) * 32 + ch * 8 + s_c8];
        }
        __syncthreads();

#pragma unroll
        for (int lc = 0; lc < 8; ++lc) {
            const int cg = ch * 8 + lc;     // global f4 column 0..31
            float4 w_k[4], w_q[4];
#pragma unroll
            for (int j = 0; j < 4; ++j) {
                w_k[j] = wk_s[(4 * d0 + j) * 32 + (cg ^ d0)];
                w_q[j] = wq_s[(4 * d0 + j) * 32 + (cg ^ d0)];
            }
#pragma unroll
            for (int i = 0; i < 8; ++i) {
                const float4 f = fs4[(ro * 8 + i) * 8 + (lc ^ (ro & 7))];
#pragma unroll
                for (int j = 0; j < 4; ++j) {
                    acc_k[i][j] += f.x * w_k[j].x + f.y * w_k[j].y + f.z * w_k[j].z + f.w * w_k[j].w;
                    acc_q[i][j] += f.x * w_q[j].x + f.y * w_q[j].y + f.z * w_q[j].z + f.w * w_q[j].w;
                }
            }
        }
    }

    // Epilogue: bias + float4 stores (8 lanes cover 128B of one output row pair)
    const float4 bk = *(const float4*)&kb[4 * d0];
    const float4 bq = *(const float4*)&qb[4 * d0];
#pragma unroll
    for (int i = 0; i < 8; ++i) {
        const long long row = blk_row + ro * 8 + i;
        float4 vk, vq;
        vk.x = acc_k[i][0] + bk.x; vk.y = acc_k[i][1] + bk.y;
        vk.z = acc_k[i][2] + bk.z; vk.w = acc_k[i][3] + bk.w;
        vq.x = acc_q[i][0] + bq.x; vq.y = acc_q[i][1] + bq.y;
        vq.z = acc_q[i][2] + bq.z; vq.w = acc_q[i][3] + bq.w;
        ((float4*)out_k)[row * (DOUT / 4) + d0] = vk;
        ((float4*)out_q)[row * (DOUT / 4) + d0] = vq;
    }
}

// ---------------------------------------------------------------------------
// Kernel 2: gather + scaled dot, cooperative-8.
// 8 lanes read one 128B table row contiguously (full cache lines per wave
// instr), dot in-lane, 3-step shfl_xor reduce, lane 0 stores.
// blockIdx%8 == batch keeps each batch's 4MB tables on one XCD's L2.
// ---------------------------------------------------------------------------
__global__ __launch_bounds__(256) void gather_dot_kernel(
    const float* __restrict__ tk, const float* __restrict__ tq,
    const int* __restrict__ idx, float* __restrict__ out)
{
    const long long NK  = (long long)NNODES * KNBR;     // 262144 outputs per batch
    const long long BNK = NK * BATCH;                   // 2097152 total

    const int b   = blockIdx.x & 7;
    const int blk = blockIdx.x >> 3;
    const int grp = threadIdx.x >> 3;   // 0..31: output group within pass
    const int j   = threadIdx.x & 7;    // f4 column within the 128B row

    const float4* tb_k = (const float4*)(tk + (long long)b * NNODES * DOUT);
    const float4* tb_q = (const float4*)(tq + (long long)b * NNODES * DOUT);

#pragma unroll
    for (int p = 0; p < 8; ++p) {
        const long long local = (long long)blk * 256 + p * 32 + grp;  // < NK
        const long long o     = (long long)b * NK + local;

        const int xi = idx[BNK + o];        // channel 1
        const int yi = idx[2 * BNK + o];    // channel 2

        const float4 x = tb_k[(long long)xi * 8 + j];
        const float4 y = tb_q[(long long)yi * 8 + j];
        float s = x.x * y.x + x.y * y.y + x.z * y.z + x.w * y.w;
        s += __shfl_xor(s, 1);
        s += __shfl_xor(s, 2);
        s += __shfl_xor(s, 4);
        if (j == 0) out[o] = s * 0.17677669529663687f;   // 32^-0.5
    }
}

// ---------------------------------------------------------------------------
extern "C" void kernel_launch(void* const* d_in, const int* in_sizes, int n_in,
                              void* d_out, int out_size, void* d_ws, size_t ws_size,
                              hipStream_t stream)
{
    const float* feats = (const float*)d_in[0];
    const float* kw    = (const float*)d_in[1];
    const float* kb    = (const float*)d_in[2];
    const float* qw    = (const float*)d_in[3];
    const float* qb    = (const float*)d_in[4];
    const int*   idx   = (const int*)d_in[5];
    float*       out   = (float*)d_out;

    // Workspace: two fp32 tables [B*N, 32] = 16 MB each
    float* tk = (float*)d_ws;
    float* tq = tk + (long long)NROWS * DOUT;

    // Kernel 1: 512 blocks x 256 threads, 256 rows/block
    proj_kernel<<<NROWS / 256, 256, 0, stream>>>(feats, kw, kb, qw, qb, tk, tq);

    // Kernel 2: 8 batches x 1024 blocks; each block: 8 passes x 32 outputs
    gather_dot_kernel<<<BATCH * (NNODES * KNBR / 256), 256, 0, stream>>>(tk, tq, idx, out);
}

// Round 4
// 149.952 us; speedup vs baseline: 2.4412x; 2.4412x over previous
//
#include <hip/hip_runtime.h>

// Problem constants
#define BATCH   8
#define NNODES  16384
#define KNBR    16
#define LATENT  128
#define DOUT    32
#define NROWS   (BATCH * NNODES)          // 131072 rows

typedef __attribute__((ext_vector_type(8))) short short8;   // 8 bf16 (4 VGPRs)
typedef __attribute__((ext_vector_type(4))) float floatx4;  // MFMA acc

__device__ __forceinline__ unsigned short f2bf(float f) {   // fp32 -> bf16 RNE
    unsigned u = __float_as_uint(f);
    u += 0x7fff + ((u >> 16) & 1);
    return (unsigned short)(u >> 16);
}

__device__ __forceinline__ float dot2bf(unsigned a, unsigned b) {
    // dot of two bf16 pairs packed in uints
    float alo = __uint_as_float(a << 16);
    float ahi = __uint_as_float(a & 0xffff0000u);
    float blo = __uint_as_float(b << 16);
    float bhi = __uint_as_float(b & 0xffff0000u);
    return alo * blo + ahi * bhi;
}

// ---------------------------------------------------------------------------
// Kernel 1: bf16 MFMA projection.  C[256 x 64] per block = feats * [kw|qw]^T.
// 4 waves; wave w computes rows [w*64, w*64+64) x all 64 cols as 4x4 tiles of
// 16x16 (K-steps of 32, total K=128 in 2 LDS chunks of 64).
// Row pads (+8 bf16 = 4 banks) make all ds accesses <=2-way (free).
// Tables stored bf16 -> per-batch gather footprint 4MB = one XCD L2.
// ---------------------------------------------------------------------------
#define APAD 72     // A chunk row stride: 64 + 8 bf16 (144 B, 16B-aligned)
#define BPAD 136    // B row stride: 128 + 8 bf16 (272 B)

__global__ __launch_bounds__(256) void proj_kernel(
    const float* __restrict__ feats,
    const float* __restrict__ kw, const float* __restrict__ kb,
    const float* __restrict__ qw, const float* __restrict__ qb,
    unsigned short* __restrict__ tkb, unsigned short* __restrict__ tqb)
{
    __shared__ unsigned short A_lds[256 * APAD];   // 36 KB
    __shared__ unsigned short B_lds[64 * BPAD];    // 17 KB
    __shared__ float bias_lds[64];

    const int tid  = threadIdx.x;
    const int lane = tid & 63;
    const int w    = tid >> 6;                     // wave 0..3
    const long long blk_row = (long long)blockIdx.x * 256;

    // Stage B = [kw ; qw] as bf16: B_lds[col*BPAD + k] = W_cat[col][k]
    {
        const float4* kw4 = (const float4*)kw;     // [32 rows][32 f4]
        const float4* qw4 = (const float4*)qw;
#pragma unroll
        for (int i = 0; i < 8; ++i) {
            const int linear = i * 256 + tid;      // 0..2047
            const int row = linear >> 5;           // 0..63
            const int c4  = linear & 31;
            const float4 v = (row < 32) ? kw4[row * 32 + c4] : qw4[(row - 32) * 32 + c4];
            unsigned lo = f2bf(v.x) | ((unsigned)f2bf(v.y) << 16);
            unsigned hi = f2bf(v.z) | ((unsigned)f2bf(v.w) << 16);
            *(uint2*)&B_lds[row * BPAD + c4 * 4] = make_uint2(lo, hi);
        }
        if (tid < 64) bias_lds[tid] = (tid < 32) ? kb[tid] : qb[tid - 32];
    }

    const int m = lane & 15;   // MFMA row (A) / col (B,C)
    const int q = lane >> 4;   // quad

    floatx4 acc[4][4];
#pragma unroll
    for (int rt = 0; rt < 4; ++rt)
#pragma unroll
        for (int ct = 0; ct < 4; ++ct) acc[rt][ct] = (floatx4){0.f, 0.f, 0.f, 0.f};

    const float4* f4 = (const float4*)feats;       // feature row = 32 f4
    const int s_c4   = tid & 15;                   // staging f4 col within chunk
    const int s_rowg = tid >> 4;                   // staging row 0..15

    for (int ch = 0; ch < 2; ++ch) {
        __syncthreads();   // prev chunk consumed (and ch0: B/bias visible via next sync)
        // Stage A chunk: 256 rows x 64 floats (k in [ch*64, ch*64+64)) -> bf16
#pragma unroll
        for (int i = 0; i < 16; ++i) {
            const int row = i * 16 + s_rowg;
            const float4 v = f4[(blk_row + row) * 32 + ch * 16 + s_c4];
            unsigned lo = f2bf(v.x) | ((unsigned)f2bf(v.y) << 16);
            unsigned hi = f2bf(v.z) | ((unsigned)f2bf(v.w) << 16);
            *(uint2*)&A_lds[row * APAD + s_c4 * 4] = make_uint2(lo, hi);
        }
        __syncthreads();

#pragma unroll
        for (int ks = 0; ks < 2; ++ks) {
            const int kk = ks * 32 + q * 8;        // k within A chunk, this lane
            const int kg = ch * 64 + kk;           // global k for B
            short8 bf[4];
#pragma unroll
            for (int ct = 0; ct < 4; ++ct)
                bf[ct] = *(const short8*)&B_lds[(ct * 16 + m) * BPAD + kg];
#pragma unroll
            for (int rt = 0; rt < 4; ++rt) {
                const short8 af = *(const short8*)&A_lds[(w * 64 + rt * 16 + m) * APAD + kk];
#pragma unroll
                for (int ct = 0; ct < 4; ++ct)
                    acc[rt][ct] = __builtin_amdgcn_mfma_f32_16x16x32_bf16(af, bf[ct], acc[rt][ct], 0, 0, 0);
            }
        }
    }

    // Epilogue: bias + bf16 store. C/D layout: col = lane&15, row = q*4+reg.
#pragma unroll
    for (int rt = 0; rt < 4; ++rt) {
#pragma unroll
        for (int reg = 0; reg < 4; ++reg) {
            const long long row = blk_row + w * 64 + rt * 16 + q * 4 + reg;
#pragma unroll
            for (int ct = 0; ct < 4; ++ct) {
                const float val = acc[rt][ct][reg] + bias_lds[ct * 16 + m];
                if (ct < 2) tkb[row * DOUT + ct * 16 + m]       = f2bf(val);
                else        tqb[row * DOUT + (ct - 2) * 16 + m] = f2bf(val);
            }
        }
    }
}

// ---------------------------------------------------------------------------
// Kernel 2: gather + scaled dot on bf16 tables, cooperative-4.
// 4 lanes read one 64B row (4 x uint4), dot in-lane, 2-step shfl reduce.
// blockIdx%8 == batch: each batch's 4MB (tk+tq bf16) fits one XCD's L2.
// ---------------------------------------------------------------------------
__global__ __launch_bounds__(256) void gather_dot_kernel(
    const unsigned short* __restrict__ tkb, const unsigned short* __restrict__ tqb,
    const int* __restrict__ idx, float* __restrict__ out)
{
    const long long NK  = (long long)NNODES * KNBR;     // 262144 per batch
    const long long BNK = NK * BATCH;                   // 2097152 total

    const int b   = blockIdx.x & 7;
    const int blk = blockIdx.x >> 3;
    const int grp = threadIdx.x >> 2;   // 0..63: output within pass
    const int j   = threadIdx.x & 3;    // uint4 column within the 64B row

    const uint4* tb_k = (const uint4*)(tkb + (long long)b * NNODES * DOUT);
    const uint4* tb_q = (const uint4*)(tqb + (long long)b * NNODES * DOUT);

#pragma unroll
    for (int p = 0; p < 4; ++p) {
        const long long local = (long long)blk * 256 + p * 64 + grp;  // < NK
        const long long o     = (long long)b * NK + local;

        const int xi = idx[BNK + o];        // channel 1
        const int yi = idx[2 * BNK + o];    // channel 2

        const uint4 x = tb_k[(long long)xi * 4 + j];
        const uint4 y = tb_q[(long long)yi * 4 + j];
        float s = dot2bf(x.x, y.x) + dot2bf(x.y, y.y)
                + dot2bf(x.z, y.z) + dot2bf(x.w, y.w);
        s += __shfl_xor(s, 1);
        s += __shfl_xor(s, 2);
        if (j == 0) out[o] = s * 0.17677669529663687f;   // 32^-0.5
    }
}

// ---------------------------------------------------------------------------
extern "C" void kernel_launch(void* const* d_in, const int* in_sizes, int n_in,
                              void* d_out, int out_size, void* d_ws, size_t ws_size,
                              hipStream_t stream)
{
    const float* feats = (const float*)d_in[0];
    const float* kw    = (const float*)d_in[1];
    const float* kb    = (const float*)d_in[2];
    const float* qw    = (const float*)d_in[3];
    const float* qb    = (const float*)d_in[4];
    const int*   idx   = (const int*)d_in[5];
    float*       out   = (float*)d_out;

    // Workspace: two bf16 tables [B*N, 32] = 8 MB each
    unsigned short* tkb = (unsigned short*)d_ws;
    unsigned short* tqb = tkb + (long long)NROWS * DOUT;

    proj_kernel<<<NROWS / 256, 256, 0, stream>>>(feats, kw, kb, qw, qb, tkb, tqb);
    gather_dot_kernel<<<(int)((long long)BATCH * NNODES * KNBR / 256), 256, 0, stream>>>(
        tkb, tqb, idx, out);
}